// Round 11
// baseline (259.912 us; speedup 1.0000x reference)
//
#include <hip/hip_runtime.h>

// DepthDeformConvPack on MI355X — round 15: collapse 5 dispatches -> 2.
// r14 post-mortem: conflicts UNCHANGED (12.86M) across 3 LDS layouts ->
// refuted; random 64-lane scatter has intrinsic statistical bank imbalance.
// K3 plateaued at ~103us. The books don't balance: K3=103 but total=243.7;
// bottom-up K1~13 + K2~18 + K0~3 + memset~2 = ~140 accounted -> ~100us of
// launch gaps / K1 atomics (1.18M device-scope) / K2<->K3 duplication.
// Changes:
//   (1) k_prep_offset: K0 grid-stride prologue + offset conv with FULL
//       320-ch reduction per block (8 waves x 40ch, LDS reduce) -> no
//       atomics, no memset, no 4x segment duplication. 256 blocks.
//   (2) k_fused_gemm: K2 absorbed as K3 prologue — the block that consumes
//       mask[n,:,ho,:] is the block that computes it. Phase M = r13 K2 body
//       (pair-load depth gather, LDS reduce aliased onto Bs/pwT/piT, sigmoid)
//       -> mskL[9][64] in LDS; phase P reads mskL; mask never touches HBM;
//       ch0-7 strip staging issued at kernel start hides under phase M.
//       Main loop = r14 verbatim (fallback reads mskL). LDS pool 101.4KB.

typedef __bf16 bf16x8 __attribute__((ext_vector_type(8)));
typedef float f32x4 __attribute__((ext_vector_type(4)));
typedef float float2_u __attribute__((ext_vector_type(2), aligned(4)));

__device__ __forceinline__ unsigned short f2bf(float f) {
  unsigned b = __float_as_uint(f);
  return (unsigned short)((b + 0x7fffu + ((b >> 16) & 1u)) >> 16);
}

// ---------------------------------------------------------------------------
// L1: fused weight-prep (K0) + offset conv (K1, full-channel, no atomics).
// 256 blocks x 512 thr; block = (n,ho); 8 waves x 40 channels each.
// ---------------------------------------------------------------------------
__global__ __launch_bounds__(512) void k_prep_offset(
    const float* __restrict__ x, const float* __restrict__ depth,
    const float* __restrict__ w, const float* __restrict__ off_w,
    const float* __restrict__ off_b,
    unsigned short* __restrict__ wbf, float* __restrict__ offs)
{
  const int tid = threadIdx.x;
  // --- K0: weight fp32 -> bf16, grid-stride (589824 elems / 131072 thr)
  for (int i = blockIdx.x * 512 + tid; i < 589824; i += 131072)
    wbf[i] = f2bf(w[i]);

  const int n = blockIdx.x >> 6, ho = blockIdx.x & 63;
  const int lane = tid & 63;              // == wo
  const int wave = tid >> 6;              // 0..7

  float acc[18];
#pragma unroll
  for (int i = 0; i < 18; ++i) acc[i] = 0.f;

  const int c0 = __builtin_amdgcn_readfirstlane(wave * 40);

  for (int ci = 0; ci < 40; ++ci) {
    const int c = c0 + ci;
    const float* p = (c < 256) ? (x + (((n << 8) + c) << 12))
                               : (depth + (((n << 6) + (c - 256)) << 12));
    const float v0 = (ho > 0)  ? p[((ho - 1) << 6) + lane] : 0.f;
    const float v1 =             p[( ho      << 6) + lane];
    const float v2 = (ho < 63) ? p[((ho + 1) << 6) + lane] : 0.f;

    float v[9];
#pragma unroll
    for (int ky = 0; ky < 3; ++ky) {
      const float r = (ky == 0) ? v0 : ((ky == 1) ? v1 : v2);
#pragma unroll
      for (int kx = 0; kx < 3; ++kx) {
        const int src = lane + kx - 1;
        const float s = __shfl(r, src & 63);
        v[ky * 3 + kx] = (src >= 0 && src < 64) ? s : 0.f;
      }
    }
    const float* wp = off_w + c * 9;   // wave-uniform address
#pragma unroll
    for (int co = 0; co < 18; ++co) {
      const float* ww = wp + co * 2880;
#pragma unroll
      for (int t = 0; t < 9; ++t) acc[co] += v[t] * ww[t];
    }
  }

  __shared__ float red[8][18][64];       // 36864 B
#pragma unroll
  for (int co = 0; co < 18; ++co) red[wave][co][lane] = acc[co];
  __syncthreads();
  for (int o = tid; o < 18 * 64; o += 512) {
    const int co = o >> 6, wo = o & 63;
    float s = off_b[co];
#pragma unroll
    for (int wv = 0; wv < 8; ++wv) s += red[wv][co][wo];
    offs[((n * 18 + co) << 12) + (ho << 6) + wo] = s;   // direct store
  }
}

// ---------------------------------------------------------------------------
// L2: fused mask deform conv (K2) + main modulated deform conv GEMM (K3).
// Block = (n,ho) via XCD swizzle, 512 thr = 8 waves, grid 256.
// Phase M: mask for this row -> mskL (LDS). Phase P: sampling params.
// Main loop: r14 (strip ring staged via per-row global_load_lds, 272B stride).
// LDS pool layout (101376 B):
//   [0      .. 78336) strip   9 x 8704
//   [78336  .. 87552) Bs      64 x 72 u16     \
//   [87552  .. 96768) pwT     9 x 64 float4    > aliased by red[8][9][64]
//   [96768  .. 99072) piT     9 x 64 int      /  (18432 B, phase-M only)
//   [99072  ..101376) mskL    9 x 64 float
// ---------------------------------------------------------------------------
__device__ __forceinline__ void stage_channel_row(const float* src, char* dstb,
                                                  int lane) {
  // 32 rows x 256B; each size-4 call writes one row (64 lanes x 4B, linear).
  const char* s = (const char*)src + lane * 4;
#pragma unroll
  for (int j = 0; j < 32; ++j)
    __builtin_amdgcn_global_load_lds(
        (const __attribute__((address_space(1))) void*)(s + j * 256),
        (__attribute__((address_space(3))) void*)(dstb + j * 272), 4, 0, 0);
}

__global__ __launch_bounds__(512, 2) void k_fused_gemm(
    const float* __restrict__ x, const float* __restrict__ depth,
    const float* __restrict__ offs, const float* __restrict__ mask_w,
    const float* __restrict__ mask_b, const unsigned short* __restrict__ wbf,
    const float* __restrict__ bias, float* __restrict__ out)
{
  __shared__ __align__(16) char pool[101376];
  char* stripc = pool;
  unsigned short (*Bs)[72]  = (unsigned short (*)[72])(pool + 78336);
  float4 (*pwT)[64]         = (float4 (*)[64])(pool + 87552);
  int (*piT)[64]            = (int (*)[64])(pool + 96768);
  float (*mskL)[64]         = (float (*)[64])(pool + 99072);
  float (*red)[9][64]       = (float (*)[9][64])(pool + 78336);  // phase-M alias

  const int tid = threadIdx.x;
  // XCD swizzle: b&7 = XCD; each XCD owns a 32-row strip of one batch.
  const int b    = blockIdx.x;            // 256 blocks
  const int xcd  = b & 7, bslot = b >> 3; // bslot 0..31
  const int n    = xcd >> 1;
  const int ho   = ((xcd & 1) << 5) + bslot;      // 0..63
  const int pxb  = ho << 6;                       // px base within batch
  const int ylo  = min(max(ho - 15, 0), 32);      // strip rows [ylo, ylo+32)

  const int pxl  = tid & 63;        // px within row (= lane)
  const int oct  = tid >> 6;        // wave id; k-octet of 8
  const int lane = tid & 63;
  const int mrow = lane & 15;
  const int koct = lane >> 4;       // 0..3 -> k-subgroup of 8
  const float* xn = x + ((long)(n << 8) << 12);

  // --- prologue: stage channels 0..7 (window of iter 0), one per wave.
  // In flight during the whole mask phase; drained at the first barrier.
  stage_channel_row(xn + (oct << 12) + (ylo << 6), stripc + oct * 8704, lane);
  int c_staged = 8;

  // =============== Phase M: mask deform conv for this (n,ho) row ===========
  {
    const int wo = lane;
    int ia[9], ib[9];
    float w0[9], w1[9], w2c[9], w3[9];
    const float* op = offs + ((n * 18) << 12) + (ho << 6) + wo;
#pragma unroll
    for (int k = 0; k < 9; ++k) {
      const float dy = op[(2 * k) << 12];
      const float dx = op[(2 * k + 1) << 12];
      const float yy = (float)(ho - 1 + k / 3) + dy;
      const float xx = (float)(wo - 1 + k % 3) + dx;
      const float y0f = floorf(yy), x0f = floorf(xx);
      const float ly = yy - y0f, lx = xx - x0f;
      const int y0 = (int)y0f, x0 = (int)x0f;
      const int y0c = min(max(y0, 0), 63);
      const int y1c = min(max(y0 + 1, 0), 63);
      const float fy0 = (y0 >= 0 && y0 < 64) ? 1.f : 0.f;
      const float fy1 = (y0 >= -1 && y0 < 63) ? 1.f : 0.f;
      const int x0c = min(max(x0, 0), 63);
      const int x1c = min(max(x0 + 1, 0), 63);
      const int bx  = min(max(x0, 0), 62);
      const float vx0 = (x0 >= 0 && x0 < 64) ? 1.f : 0.f;
      const float vx1 = (x0 >= -1 && x0 < 63) ? 1.f : 0.f;
      const float wl = (1.f - lx) * vx0 * ((x0c == bx) ? 1.f : 0.f)
                     + lx * vx1 * ((x1c == bx) ? 1.f : 0.f);
      const float wr = (1.f - lx) * vx0 * ((x0c == bx + 1) ? 1.f : 0.f)
                     + lx * vx1 * ((x1c == bx + 1) ? 1.f : 0.f);
      const float a0 = (1.f - ly) * fy0;
      const float a1 = ly * fy1;
      ia[k] = ((y0c << 6) + bx) << 2;
      ib[k] = ((y1c << 6) + bx) << 2;
      w0[k] = wl * a0;  w1[k] = wr * a0;
      w2c[k] = wl * a1; w3[k] = wr * a1;
    }

    float acc2[9];
#pragma unroll
    for (int i = 0; i < 9; ++i) acc2[i] = 0.f;

    const int cbase = __builtin_amdgcn_readfirstlane(oct * 8);
    for (int cc = 0; cc < 8; ++cc) {
      const int c = cbase + cc;
      const char* p = (const char*)(depth + (((n << 6) + c) << 12));
      float val[9];
#pragma unroll
      for (int k = 0; k < 9; ++k) {
        const float2_u A = *(const float2_u*)(p + ia[k]);
        const float2_u B = *(const float2_u*)(p + ib[k]);
        val[k] = A.x * w0[k] + A.y * w1[k] + B.x * w2c[k] + B.y * w3[k];
      }
      const float* wp = mask_w + c * 9;
#pragma unroll
      for (int co = 0; co < 9; ++co) {
#pragma unroll
        for (int k = 0; k < 9; ++k) acc2[co] += val[k] * wp[co * 576 + k];
      }
    }
#pragma unroll
    for (int co = 0; co < 9; ++co) red[oct][co][lane] = acc2[co];
  }
  __syncthreads();   // red complete (also drains prologue staging vmcnt)

  for (int o = tid; o < 576; o += 512) {
    const int co = o >> 6, wo = o & 63;
    float s = mask_b[co];
#pragma unroll
    for (int wv = 0; wv < 8; ++wv) s += red[wv][co][wo];
    mskL[co][wo] = 1.f / (1.f + expf(-s));
  }
  __syncthreads();   // mskL ready; red dead -> Bs/pwT/piT region free

  // =============== Phase P: sampling params into LDS tables ================
  for (int e = tid; e < 576; e += 512) {
    const int tap = e >> 6, pl = e & 63;
    const int wo = pl;
    const float dy = offs[((n * 18 + 2 * tap) << 12) + pxb + pl];
    const float dx = offs[((n * 18 + 2 * tap + 1) << 12) + pxb + pl];
    const float m  = mskL[tap][pl];
    const float yy = (float)(ho - 1 + tap / 3) + dy;
    const float xx = (float)(wo - 1 + tap % 3) + dx;
    const float y0f = floorf(yy), x0f = floorf(xx);
    const float ly = yy - y0f, lx = xx - x0f;
    const int y0 = (int)y0f, x0 = (int)x0f;
    const int y0c = min(max(y0, 0), 63);
    const int y1c = min(max(y0 + 1, 0), 63);
    const float fy0 = (y0 >= 0 && y0 < 64) ? 1.f : 0.f;
    const float fy1 = (y0 >= -1 && y0 < 63) ? 1.f : 0.f;
    const int x0c = min(max(x0, 0), 63);
    const int x1c = min(max(x0 + 1, 0), 63);
    const int bx  = min(max(x0, 0), 62);
    const float vx0 = (x0 >= 0 && x0 < 64) ? 1.f : 0.f;
    const float vx1 = (x0 >= -1 && x0 < 63) ? 1.f : 0.f;
    const float wl = (1.f - lx) * vx0 * ((x0c == bx) ? 1.f : 0.f)
                   + lx * vx1 * ((x1c == bx) ? 1.f : 0.f);
    const float wr = (1.f - lx) * vx0 * ((x0c == bx + 1) ? 1.f : 0.f)
                   + lx * vx1 * ((x1c == bx + 1) ? 1.f : 0.f);
    const float a0 = (1.f - ly) * fy0 * m;
    const float a1 = ly * fy1 * m;
    pwT[tap][pl] = make_float4(wl * a0, wr * a0, wl * a1, wr * a1);
    // strip-relative byte addrs (row stride 272B) + bad flag
    const int ry0 = y0c - ylo, ry1 = y1c - ylo;
    const int ry0c = min(max(ry0, 0), 31), ry1c = min(max(ry1, 0), 31);
    const int bad = ((ry0 != ry0c) || (ry1 != ry1c)) ? 1 : 0;
    const int ad0 = ry0c * 272 + (bx << 2);      // <= 8680 < 16384
    const int ad1 = ry1c * 272 + (bx << 2);
    piT[tap][pl] = ad0 | (ad1 << 14) | (bad << 28);
  }
  __syncthreads();   // params + prologue strip visible

  // --- gather: one k-octet (8 k) per lane into Bs; params from LDS tables.
  auto gather = [&](int ic) {
    const int k0 = (ic << 6) + (oct << 3);
    const int c0 = (int)(((unsigned)k0 * 7282u) >> 16);    // k0/9
    int tap = k0 - 9 * c0;
    const int s9 = (int)(((unsigned)c0 * 7282u) >> 16);    // c0/9
    int soff = (c0 - 9 * s9) * 8704;                       // slot byte offset

    __align__(16) unsigned short v[8];
    unsigned badm = 0;
#pragma unroll
    for (int j = 0; j < 8; ++j) {
      const int pk  = piT[tap][pxl];              // ds_read_b32
      const float4 w = pwT[tap][pxl];             // ds_read_b128
      const float2_u A = *(const float2_u*)(stripc + soff + (pk & 16383));
      const float2_u B = *(const float2_u*)(stripc + soff + ((pk >> 14) & 16383));
      v[j] = f2bf(A.x * w.x + A.y * w.y + B.x * w.z + B.y * w.w);
      badm |= ((unsigned)pk >> 28) << j;          // bit28 = bad
      if (++tap == 9) {
        tap = 0;
        soff += 8704; if (soff == 9 * 8704) soff = 0;
      }
    }

    if (__builtin_expect(badm != 0, 0)) {         // ~10 events per launch
#pragma unroll
      for (int j = 0; j < 8; ++j) if (badm & (1u << j)) {
        const int k = k0 + j;
        const int c = (int)(((unsigned)k * 7282u) >> 16);
        const int tp = k - 9 * c;
        // full recompute from global (identical math to phase P)
        const float dy = offs[((n * 18 + 2 * tp) << 12) + pxb + pxl];
        const float dx = offs[((n * 18 + 2 * tp + 1) << 12) + pxb + pxl];
        const float m  = mskL[tp][pxl];
        const float yy = (float)(ho - 1 + tp / 3) + dy;
        const float xx = (float)(pxl - 1 + tp % 3) + dx;
        const float y0f = floorf(yy), x0f = floorf(xx);
        const float ly = yy - y0f, lx = xx - x0f;
        const int y0 = (int)y0f, x0 = (int)x0f;
        const int y0c = min(max(y0, 0), 63);
        const int y1c = min(max(y0 + 1, 0), 63);
        const float fy0 = (y0 >= 0 && y0 < 64) ? 1.f : 0.f;
        const float fy1 = (y0 >= -1 && y0 < 63) ? 1.f : 0.f;
        const int x0c = min(max(x0, 0), 63);
        const int x1c = min(max(x0 + 1, 0), 63);
        const int bx  = min(max(x0, 0), 62);
        const float vx0 = (x0 >= 0 && x0 < 64) ? 1.f : 0.f;
        const float vx1 = (x0 >= -1 && x0 < 63) ? 1.f : 0.f;
        const float wl = (1.f - lx) * vx0 * ((x0c == bx) ? 1.f : 0.f)
                       + lx * vx1 * ((x1c == bx) ? 1.f : 0.f);
        const float wr = (1.f - lx) * vx0 * ((x0c == bx + 1) ? 1.f : 0.f)
                       + lx * vx1 * ((x1c == bx + 1) ? 1.f : 0.f);
        const float a0 = (1.f - ly) * fy0 * m;
        const float a1 = ly * fy1 * m;
        const char* pg = (const char*)xn + ((long)c << 14);
        const float2_u Ag = *(const float2_u*)(pg + (((y0c << 6) + bx) << 2));
        const float2_u Bg = *(const float2_u*)(pg + (((y1c << 6) + bx) << 2));
        v[j] = f2bf(Ag.x * (wl * a0) + Ag.y * (wr * a0) +
                    Bg.x * (wl * a1) + Bg.y * (wr * a1));
      }
    }
    *(int4*)&Bs[pxl][oct << 3] = *(const int4*)v;
  };

  // A-fragment prefetch registers for iter 0
  bf16x8 afc[2][2];
#pragma unroll
  for (int mt = 0; mt < 2; ++mt)
#pragma unroll
    for (int ks = 0; ks < 2; ++ks) {
      const int row = (oct << 5) + (mt << 4) + mrow;
      const int col = (ks << 5) + (koct << 3);
      afc[mt][ks] = *(const bf16x8*)(wbf + row * 2304 + col);
    }

  gather(0);
  __syncthreads();

  f32x4 acc[2][4];
#pragma unroll
  for (int mt = 0; mt < 2; ++mt)
#pragma unroll
    for (int nt = 0; nt < 4; ++nt)
#pragma unroll
      for (int r = 0; r < 4; ++r) acc[mt][nt][r] = 0.f;

  for (int ic = 0; ic < 36; ++ic) {
    // stage next window (overlaps MFMA; drained at barrier) + af prefetch
    if (ic < 35) {
      const int c_end = (64 * ic + 127) / 9;          // c_hi(ic+1) <= 255
      const int cw = c_staged + oct;
      if (cw <= c_end) {
        const int slt = cw - 9 * (int)(((unsigned)cw * 7282u) >> 16);
        stage_channel_row(xn + (cw << 12) + (ylo << 6),
                          stripc + slt * 8704, lane);
      }
      c_staged = c_end + 1;
    }

    bf16x8 afn[2][2];
    if (ic < 35) {
      const int kc = (ic + 1) << 6;
#pragma unroll
      for (int mt = 0; mt < 2; ++mt)
#pragma unroll
        for (int ks = 0; ks < 2; ++ks) {
          const int row = (oct << 5) + (mt << 4) + mrow;
          const int col = kc + (ks << 5) + (koct << 3);
          afn[mt][ks] = *(const bf16x8*)(wbf + row * 2304 + col);
        }
    }

#pragma unroll
    for (int ks = 0; ks < 2; ++ks)
#pragma unroll
      for (int nt = 0; nt < 4; ++nt) {
        const bf16x8 bfr =
            *(const bf16x8*)&Bs[(nt << 4) + mrow][(ks << 5) + (koct << 3)];
        acc[0][nt] = __builtin_amdgcn_mfma_f32_16x16x32_bf16(afc[0][ks], bfr,
                                                             acc[0][nt], 0, 0, 0);
        acc[1][nt] = __builtin_amdgcn_mfma_f32_16x16x32_bf16(afc[1][ks], bfr,
                                                             acc[1][nt], 0, 0, 0);
      }

    __syncthreads();           // drains stage; Bs free for rewrite
    if (ic < 35) gather(ic + 1);
    __syncthreads();           // Bs ready for next MFMA; strip safe to restage

#pragma unroll
    for (int mt = 0; mt < 2; ++mt)
#pragma unroll
      for (int ks = 0; ks < 2; ++ks) afc[mt][ks] = afn[mt][ks];
  }

  // epilogue: C/D layout col=lane&15 (px), row=(lane>>4)*4+r (co)
#pragma unroll
  for (int mt = 0; mt < 2; ++mt)
#pragma unroll
    for (int nt = 0; nt < 4; ++nt)
#pragma unroll
      for (int r = 0; r < 4; ++r) {
        const int co = (oct << 5) + (mt << 4) + ((lane >> 4) << 2) + r;
        const int pxg = pxb + (nt << 4) + (lane & 15);
        out[(((n << 8) + co) << 12) + pxg] = acc[mt][nt][r] + bias[co];
      }
}

// ---------------------------------------------------------------------------
extern "C" void kernel_launch(void* const* d_in, const int* in_sizes, int n_in,
                              void* d_out, int out_size, void* d_ws, size_t ws_size,
                              hipStream_t stream) {
  const float* x      = (const float*)d_in[0];
  const float* depth  = (const float*)d_in[1];
  const float* weight = (const float*)d_in[2];
  const float* bias   = (const float*)d_in[3];
  const float* off_w  = (const float*)d_in[4];
  const float* off_b  = (const float*)d_in[5];
  const float* mask_w = (const float*)d_in[6];
  const float* mask_b = (const float*)d_in[7];
  float* out = (float*)d_out;

  float* offs = (float*)d_ws;                              // 294912 floats
  unsigned short* wbf = (unsigned short*)(offs + 294912);  // 589824 bf16

  k_prep_offset<<<256, 512, 0, stream>>>(x, depth, weight, off_w, off_b,
                                         wbf, offs);
  k_fused_gemm<<<256, 512, 0, stream>>>(x, depth, offs, mask_w, mask_b,
                                        wbf, bias, out);
}